// Round 1
// baseline (339.228 us; speedup 1.0000x reference)
//
#include <hip/hip_runtime.h>
#include <math.h>

// Problem constants (LinOSSBlock: B=16, N=8192, M=128, dt=1)
#define Bdim   16
#define Nseq   8192
#define Mdim   128
#define BNROWS (Bdim * Nseq)        // 131072 GEMM rows
#define CHUNKS 64
#define CLEN   (Nseq / CHUNKS)      // 128 steps per chunk
#define CHAINS (Bdim * Mdim)        // 2048 independent scan chains

typedef __bf16 bf16;
typedef __bf16 bf16x8 __attribute__((ext_vector_type(8)));
typedef __bf16 bf16x4 __attribute__((ext_vector_type(4)));
typedef float  f32x4  __attribute__((ext_vector_type(4)));

// ---------------------------------------------------------------------------
// helpers
// ---------------------------------------------------------------------------
static __device__ __forceinline__ float gelu_exact(float x) {
    return 0.5f * x * (1.0f + erff(x * 0.70710678118654752f));
}

// stage a 128x128 f32 tile (rowBase offset in rows) -> bf16 LDS [128][128]
static __device__ __forceinline__ void stage_f32_tile(const float* __restrict__ g,
                                                      size_t rowBase, bf16* lds, int tid) {
    for (int i = tid; i < 128 * 32; i += 256) {
        int r  = i >> 5;
        int c4 = i & 31;
        float4 v = ((const float4*)g)[(rowBase + (size_t)r) * 32 + c4];
        bf16x4 p;
        p[0] = (bf16)v.x; p[1] = (bf16)v.y; p[2] = (bf16)v.z; p[3] = (bf16)v.w;
        *reinterpret_cast<bf16x4*>(&lds[r * 128 + c4 * 4]) = p;
    }
}

// stage a 128x128 bf16 tile -> LDS [128][128]
static __device__ __forceinline__ void stage_bf16_tile(const bf16* __restrict__ g,
                                                       size_t rowBase, bf16* lds, int tid) {
    for (int i = tid; i < 128 * 16; i += 256) {
        int r  = i >> 4;
        int c8 = i & 15;
        bf16x8 v = *reinterpret_cast<const bf16x8*>(&g[(rowBase + (size_t)r) * 128 + c8 * 8]);
        *reinterpret_cast<bf16x8*>(&lds[r * 128 + c8 * 8]) = v;
    }
}

// One K=128 MFMA pass: C[128 rows x 128 cols] += lA * lW^T
// wave handles rows [wave*32, wave*32+32); acc[it][j]: it = 16-row tile, j = 16-col tile
// Verified gfx950 layouts (m89/m91): A/B frag lane L holds row (L&15), k=(L>>4)*8+j;
// C/D: col = L&15, row = (L>>4)*4 + reg.
static __device__ __forceinline__ void mfma_pass(const bf16* lA, const bf16* lW,
                                                 f32x4 acc[2][8], int wave, int lane) {
    const int llo = lane & 15;
    const int lhi = lane >> 4;
    const int r0  = wave * 32;
#pragma unroll
    for (int kk = 0; kk < 4; ++kk) {
        const int k0 = kk * 32 + lhi * 8;
        bf16x8 a0 = *reinterpret_cast<const bf16x8*>(&lA[(r0 + llo) * 128 + k0]);
        bf16x8 a1 = *reinterpret_cast<const bf16x8*>(&lA[(r0 + 16 + llo) * 128 + k0]);
#pragma unroll
        for (int j = 0; j < 8; ++j) {
            bf16x8 b = *reinterpret_cast<const bf16x8*>(&lW[(j * 16 + llo) * 128 + k0]);
            acc[0][j] = __builtin_amdgcn_mfma_f32_16x16x32_bf16(a0, b, acc[0][j], 0, 0, 0);
            acc[1][j] = __builtin_amdgcn_mfma_f32_16x16x32_bf16(a1, b, acc[1][j], 0, 0, 0);
        }
    }
}

// ---------------------------------------------------------------------------
// K1: fz = u @ Bw^T + Bb   (dt = 1)   -> bf16
// ---------------------------------------------------------------------------
__global__ __launch_bounds__(256) void k1_fz(const float* __restrict__ u,
                                             const float* __restrict__ Bw,
                                             const float* __restrict__ Bb,
                                             bf16* __restrict__ fz) {
    __shared__ bf16 lA[128 * 128];
    __shared__ bf16 lW[128 * 128];
    const int tid  = threadIdx.x;
    const int lane = tid & 63;
    const int wave = tid >> 6;
    const int llo  = lane & 15;
    const int lhi  = lane >> 4;
    const size_t rowBase = (size_t)blockIdx.x * 128;

    stage_f32_tile(u, rowBase, lA, tid);
    stage_f32_tile(Bw, 0, lW, tid);
    __syncthreads();

    f32x4 acc[2][8];
#pragma unroll
    for (int it = 0; it < 2; ++it)
#pragma unroll
        for (int j = 0; j < 8; ++j) acc[it][j] = (f32x4){0.f, 0.f, 0.f, 0.f};

    mfma_pass(lA, lW, acc, wave, lane);

#pragma unroll
    for (int j = 0; j < 8; ++j) {
        const int   col = j * 16 + llo;
        const float bb  = Bb[col];
#pragma unroll
        for (int it = 0; it < 2; ++it) {
#pragma unroll
            for (int r = 0; r < 4; ++r) {
                const int row = wave * 32 + it * 16 + lhi * 4 + r;
                fz[(rowBase + row) * 128 + col] = (bf16)(acc[it][j][r] + bb);
            }
        }
    }
}

// ---------------------------------------------------------------------------
// Scan: x_i = S x_{i-1} + v f_i with constant per-m 2x2 S (block-parallel, 3 phases)
//   a = relu(A_diag), s = 1/(1+a);  zp = z+f;  z' = s*zp - s*a*y;  y' = s*(zp+y)
// ---------------------------------------------------------------------------
__global__ __launch_bounds__(256) void scan_p1(const bf16* __restrict__ fz,
                                               const float* __restrict__ Ad,
                                               float2* __restrict__ stateE) {
    const int tid  = threadIdx.x;
    const int m    = tid & 127;
    const int half = tid >> 7;
    const int b    = blockIdx.x >> 5;
    const int c    = ((blockIdx.x & 31) << 1) | half;

    const float a  = fmaxf(Ad[m], 0.f);
    const float s  = 1.f / (1.f + a);
    const float sa = s * a;

    const bf16* p = fz + ((size_t)b * Nseq + (size_t)c * CLEN) * Mdim + m;
    float z = 0.f, y = 0.f;
#pragma unroll 8
    for (int t = 0; t < CLEN; ++t) {
        float f  = (float)p[t * Mdim];
        float zp = z + f;
        float yn = s * (zp + y);
        z = s * zp - sa * y;
        y = yn;
    }
    stateE[c * CHAINS + b * Mdim + m] = make_float2(z, y);
}

__global__ __launch_bounds__(256) void scan_p2(const float2* __restrict__ stateE,
                                               const float* __restrict__ Ad,
                                               float2* __restrict__ stateS) {
    const int chain = blockIdx.x * 256 + threadIdx.x;
    const int m     = chain & 127;
    const float a   = fmaxf(Ad[m], 0.f);
    const float s   = 1.f / (1.f + a);
    // P = S^CLEN (CLEN = 128 = 2^7) by repeated squaring
    float p00 = s, p01 = -s * a, p10 = s, p11 = s;
#pragma unroll
    for (int i = 0; i < 7; ++i) {
        float q00 = p00 * p00 + p01 * p10;
        float q01 = p00 * p01 + p01 * p11;
        float q10 = p10 * p00 + p11 * p10;
        float q11 = p10 * p01 + p11 * p11;
        p00 = q00; p01 = q01; p10 = q10; p11 = q11;
    }
    float tz = 0.f, ty = 0.f;
    for (int c = 0; c < CHUNKS; ++c) {
        stateS[c * CHAINS + chain] = make_float2(tz, ty);
        float2 e = stateE[c * CHAINS + chain];
        float nz = p00 * tz + p01 * ty + e.x;
        float ny = p10 * tz + p11 * ty + e.y;
        tz = nz; ty = ny;
    }
}

__global__ __launch_bounds__(256) void scan_p3(const bf16* __restrict__ fz,
                                               const float* __restrict__ Ad,
                                               const float2* __restrict__ stateS,
                                               bf16* __restrict__ x) {
    const int tid  = threadIdx.x;
    const int m    = tid & 127;
    const int half = tid >> 7;
    const int b    = blockIdx.x >> 5;
    const int c    = ((blockIdx.x & 31) << 1) | half;

    const float a  = fmaxf(Ad[m], 0.f);
    const float s  = 1.f / (1.f + a);
    const float sa = s * a;

    const size_t off = ((size_t)b * Nseq + (size_t)c * CLEN) * Mdim + m;
    const bf16* p = fz + off;
    bf16*       q = x + off;
    float2 st = stateS[c * CHAINS + b * Mdim + m];
    float z = st.x, y = st.y;
#pragma unroll 8
    for (int t = 0; t < CLEN; ++t) {
        float f  = (float)p[t * Mdim];
        float zp = z + f;
        float yn = s * (zp + y);
        z = s * zp - sa * y;
        y = yn;
        q[t * Mdim] = (bf16)y;
    }
}

// ---------------------------------------------------------------------------
// K3: h = gelu(x @ Cw^T + u @ Dw^T + Cb + Db)  -> bf16 (overwrites fz buffer)
// ---------------------------------------------------------------------------
__global__ __launch_bounds__(256) void k3_h(const bf16* __restrict__ x,
                                            const float* __restrict__ u,
                                            const float* __restrict__ Cw,
                                            const float* __restrict__ Cb,
                                            const float* __restrict__ Dw,
                                            const float* __restrict__ Db,
                                            bf16* __restrict__ h) {
    __shared__ bf16 lA[128 * 128];
    __shared__ bf16 lW[128 * 128];
    const int tid  = threadIdx.x;
    const int lane = tid & 63;
    const int wave = tid >> 6;
    const int llo  = lane & 15;
    const int lhi  = lane >> 4;
    const size_t rowBase = (size_t)blockIdx.x * 128;

    f32x4 acc[2][8];
#pragma unroll
    for (int it = 0; it < 2; ++it)
#pragma unroll
        for (int j = 0; j < 8; ++j) acc[it][j] = (f32x4){0.f, 0.f, 0.f, 0.f};

    // pass 1: x @ Cw^T
    stage_bf16_tile(x, rowBase, lA, tid);
    stage_f32_tile(Cw, 0, lW, tid);
    __syncthreads();
    mfma_pass(lA, lW, acc, wave, lane);
    __syncthreads();

    // pass 2: + u @ Dw^T
    stage_f32_tile(u, rowBase, lA, tid);
    stage_f32_tile(Dw, 0, lW, tid);
    __syncthreads();
    mfma_pass(lA, lW, acc, wave, lane);

#pragma unroll
    for (int j = 0; j < 8; ++j) {
        const int   col = j * 16 + llo;
        const float bb  = Cb[col] + Db[col];
#pragma unroll
        for (int it = 0; it < 2; ++it) {
#pragma unroll
            for (int r = 0; r < 4; ++r) {
                const int row = wave * 32 + it * 16 + lhi * 4 + r;
                float v = acc[it][j][r] + bb;
                h[(rowBase + row) * 128 + col] = (bf16)gelu_exact(v);
            }
        }
    }
}

// ---------------------------------------------------------------------------
// K4: out = (h @ W1^T + b1) * sigmoid(h @ W2^T + b2) + u   -> f32
// ---------------------------------------------------------------------------
__global__ __launch_bounds__(256) void k4_out(const bf16* __restrict__ h,
                                              const float* __restrict__ W1,
                                              const float* __restrict__ b1,
                                              const float* __restrict__ W2,
                                              const float* __restrict__ b2,
                                              const float* __restrict__ u,
                                              float* __restrict__ out) {
    __shared__ bf16 lA[128 * 128];
    __shared__ bf16 lW[128 * 128];
    const int tid  = threadIdx.x;
    const int lane = tid & 63;
    const int wave = tid >> 6;
    const int llo  = lane & 15;
    const int lhi  = lane >> 4;
    const size_t rowBase = (size_t)blockIdx.x * 128;

    f32x4 acc1[2][8], acc2[2][8];
#pragma unroll
    for (int it = 0; it < 2; ++it)
#pragma unroll
        for (int j = 0; j < 8; ++j) {
            acc1[it][j] = (f32x4){0.f, 0.f, 0.f, 0.f};
            acc2[it][j] = (f32x4){0.f, 0.f, 0.f, 0.f};
        }

    stage_bf16_tile(h, rowBase, lA, tid);
    stage_f32_tile(W1, 0, lW, tid);
    __syncthreads();
    mfma_pass(lA, lW, acc1, wave, lane);
    __syncthreads();

    stage_f32_tile(W2, 0, lW, tid);
    __syncthreads();
    mfma_pass(lA, lW, acc2, wave, lane);

#pragma unroll
    for (int j = 0; j < 8; ++j) {
        const int   col = j * 16 + llo;
        const float bb1 = b1[col];
        const float bb2 = b2[col];
#pragma unroll
        for (int it = 0; it < 2; ++it) {
#pragma unroll
            for (int r = 0; r < 4; ++r) {
                const int row = wave * 32 + it * 16 + lhi * 4 + r;
                const size_t idx = (rowBase + row) * 128 + col;
                float t1 = acc1[it][j][r] + bb1;
                float t2 = acc2[it][j][r] + bb2;
                float g  = t1 * (1.f / (1.f + expf(-t2)));
                out[idx] = g + u[idx];
            }
        }
    }
}

// ---------------------------------------------------------------------------
// launch
// ---------------------------------------------------------------------------
extern "C" void kernel_launch(void* const* d_in, const int* in_sizes, int n_in,
                              void* d_out, int out_size, void* d_ws, size_t ws_size,
                              hipStream_t stream) {
    const float* u  = (const float*)d_in[0];
    const float* Ad = (const float*)d_in[1];
    const float* Bw = (const float*)d_in[2];
    const float* Bb = (const float*)d_in[3];
    const float* Cw = (const float*)d_in[4];
    const float* Cb = (const float*)d_in[5];
    const float* Dw = (const float*)d_in[6];
    const float* Db = (const float*)d_in[7];
    const float* W1 = (const float*)d_in[8];
    const float* b1 = (const float*)d_in[9];
    const float* W2 = (const float*)d_in[10];
    const float* b2 = (const float*)d_in[11];
    float* out = (float*)d_out;

    char* ws = (char*)d_ws;
    bf16*   fz  = (bf16*)ws;                                        // 32 MB (reused as h)
    bf16*   x   = (bf16*)(ws + (size_t)BNROWS * Mdim * 2);          // 32 MB
    float2* stE = (float2*)(ws + (size_t)BNROWS * Mdim * 4);        // 1 MB
    float2* stS = stE + (size_t)CHAINS * CHUNKS;                    // 1 MB

    k1_fz<<<BNROWS / 128, 256, 0, stream>>>(u, Bw, Bb, fz);
    scan_p1<<<512, 256, 0, stream>>>(fz, Ad, stE);
    scan_p2<<<CHAINS / 256, 256, 0, stream>>>(stE, Ad, stS);
    scan_p3<<<512, 256, 0, stream>>>(fz, Ad, stS, x);
    bf16* h = fz;  // fz dead after scan_p3; reuse as h
    k3_h<<<BNROWS / 128, 256, 0, stream>>>(x, u, Cw, Cb, Dw, Db, h);
    k4_out<<<BNROWS / 128, 256, 0, stream>>>(h, W1, b1, W2, b2, u, out);
}